// Round 6
// baseline (122.878 us; speedup 1.0000x reference)
//
#include <hip/hip_runtime.h>
#include <stdint.h>

// Problem constants (fixed by the reference)
#define NB    32768   // batch
#define NS    16      // states per element
#define SS    32      // state size (K of stage 1)
#define ENCD  64      // encoder width
#define HIDD  128     // hidden width
#define OUTD  8       // output logits
#define BT    16      // batch elements per block == per wave
#define THREADS 64    // ONE wave per block: no cross-wave sync anywhere

typedef _Float16 half8 __attribute__((ext_vector_type(8)));  // 8 f16 = 4 VGPRs
typedef float    f32x4 __attribute__((ext_vector_type(4)));

#define MFMA(a, b, c) __builtin_amdgcn_mfma_f32_16x16x32_f16((a), (b), (c), 0, 0, 0)

// 8 floats -> 8 fp16 (RNE)
__device__ __forceinline__ half8 pack8(const float* f) {
  half8 h;
#pragma unroll
  for (int j = 0; j < 8; ++j) h[j] = (_Float16)f[j];
  return h;
}

// R6 structure: wave-independent. Each 64-thread block = one wave owning 16
// batch elements end-to-end (stage1 enc-MFMA + pool, stage3 hidden, stage4
// logits). LDS is wave-private; __syncthreads with 1 wave is just a waitcnt.
// 2048 blocks -> 8 symmetric waves/CU, no early-exit asymmetry, no barrier
// convoys (R5 post-mortem: structure-bound, not VALU/BW-bound).
__global__ __launch_bounds__(THREADS, 2)
void gnn_fused(const float* __restrict__ obs,
               const float* __restrict__ W_enc,
               const float* __restrict__ b_enc,
               const float* __restrict__ W_f,
               const float* __restrict__ b_f,
               const float* __restrict__ W_dec,
               const float* __restrict__ b_dec,
               float* __restrict__ out)
{
  // fp16 LDS, row stride 136 halfs = 272 B (16B-aligned rows, bank-skewed)
  __shared__ __align__(16) _Float16 f_in[BT][136];  // stage-2 out [batch][128]
  __shared__ __align__(16) _Float16 hidn[BT][136];  // stage-3 out [batch][128]

  const int l    = threadIdx.x;  // lane 0..63
  const int m15  = l & 15;
  const int quad = l >> 4;
  const int b0   = blockIdx.x * BT;

  // ---- issue obs prefetch for elements 0..3 FIRST (longest latency)
  const float* bp = obs + (size_t)b0 * (NS * SS) + m15 * SS + quad * 8;
  float4 s0[4], s1[4];
#pragma unroll
  for (int d = 0; d < 4; ++d) {
    const float* p = bp + (size_t)d * (NS * SS);
    s0[d] = ((const float4*)p)[0];
    s1[d] = ((const float4*)p)[1];
  }

  // ---- weights/biases (latency hidden behind obs loads)
  half8 we[4], wd[4];
  float benc[4];
#pragma unroll
  for (int nt = 0; nt < 4; ++nt) {
    float f[8];
#pragma unroll
    for (int j = 0; j < 8; ++j)
      f[j] = W_enc[(size_t)(quad * 8 + j) * ENCD + nt * 16 + m15];
    we[nt]   = pack8(f);
    benc[nt] = b_enc[nt * 16 + m15];
  }
#pragma unroll
  for (int ks = 0; ks < 4; ++ks) {             // W_dec B-frags, N padded 8->16
    float f[8];
#pragma unroll
    for (int j = 0; j < 8; ++j)
      f[j] = (m15 < OUTD) ? W_dec[(size_t)(ks * 32 + quad * 8 + j) * OUTD + m15] : 0.f;
    wd[ks] = pack8(f);
  }

  // ================= stage 1 (enc MFMA) + stage 2 (masked mean-pool) =========
  // lane's A-fragment = states[b][m15][quad*8 .. +8), 4-deep rotating prefetch
#pragma unroll 4
  for (int i = 0; i < BT; ++i) {
    const int sl = i & 3;
    float f[8] = {s0[sl].x, s0[sl].y, s0[sl].z, s0[sl].w,
                  s1[sl].x, s1[sl].y, s1[sl].z, s1[sl].w};
    if (i + 4 < BT) {                           // refill slot
      const float* p = bp + (size_t)(i + 4) * (NS * SS);
      s0[sl] = ((const float4*)p)[0];
      s1[sl] = ((const float4*)p)[1];
    }

    // flags: lanes 0..15 hold states[b][n][0]; cumprod run via ballot+ctz
    unsigned long long bal = __ballot((l < 16) && (f[0] == 1.0f));
    int run = __builtin_ctzll(~(bal >> 1));     // consecutive valid neighbors
    float inv = 1.0f / fmaxf((float)run, 1.0f);

    half8 a = pack8(f);
#pragma unroll
    for (int nt = 0; nt < 4; ++nt) {
      f32x4 acc = {0.f, 0.f, 0.f, 0.f};
      acc = MFMA(a, we[nt], acc);
      // D layout: lane holds enc[n = quad*4 + r][e = nt*16 + m15]
      float s = 0.f, e0 = 0.f;
#pragma unroll
      for (int r = 0; r < 4; ++r) {
        int n = quad * 4 + r;
        float v = fmaxf(acc[r] + benc[nt], 0.f);
        if (n == 0) e0 = v;                     // agent row
        if (n >= 1 && n <= run) s += v;         // valid neighbor
      }
      s += __shfl_xor(s, 16, 64);               // reduce across quads
      s += __shfl_xor(s, 32, 64);
      if (quad == 0) {
        f_in[i][nt * 16 + m15]      = (_Float16)e0;        // agent_enc
        f_in[i][64 + nt * 16 + m15] = (_Float16)(s * inv); // agg
      }
    }
  }
  __syncthreads();   // single-wave: compiles to waitcnt + trivial barrier

  // ================= stage 3: hidden = relu(f_in @ W_f + b_f) ================
  // this wave's 16-row M-tile x all 8 N-tiles
  {
    half8 fa[4];
#pragma unroll
    for (int ks = 0; ks < 4; ++ks)              // A-frag: one 16B LDS read
      fa[ks] = *(const half8*)&f_in[m15][ks * 32 + quad * 8];

#pragma unroll
    for (int tt = 0; tt < 8; ++tt) {
      const int h0 = tt * 16 + m15;             // output column
      f32x4 acc = {0.f, 0.f, 0.f, 0.f};
#pragma unroll
      for (int ks = 0; ks < 4; ++ks) {
        float f[8];
#pragma unroll
        for (int j = 0; j < 8; ++j)             // W_f column chunk (L1/L2 hot)
          f[j] = W_f[(size_t)(ks * 32 + quad * 8 + j) * HIDD + h0];
        acc = MFMA(fa[ks], pack8(f), acc);
      }
      const float bfv = b_f[h0];
#pragma unroll
      for (int r = 0; r < 4; ++r)               // D: row = batch, col = h0
        hidn[quad * 4 + r][h0] = (_Float16)fmaxf(acc[r] + bfv, 0.f);
    }
  }
  __syncthreads();

  // ================= stage 4: logits = hidden @ W_dec + b_dec ================
  {
    half8 ga[4];
#pragma unroll
    for (int ks = 0; ks < 4; ++ks)
      ga[ks] = *(const half8*)&hidn[m15][ks * 32 + quad * 8];
    f32x4 acc = {0.f, 0.f, 0.f, 0.f};
#pragma unroll
    for (int ks = 0; ks < 4; ++ks)
      acc = MFMA(ga[ks], wd[ks], acc);
    if (m15 < OUTD) {
      const float bd = b_dec[m15];
#pragma unroll
      for (int r = 0; r < 4; ++r) {
        const int m = quad * 4 + r;
        out[(size_t)(b0 + m) * OUTD + m15] = acc[r] + bd;
      }
    }
  }
}

extern "C" void kernel_launch(void* const* d_in, const int* in_sizes, int n_in,
                              void* d_out, int out_size, void* d_ws, size_t ws_size,
                              hipStream_t stream) {
  (void)in_sizes; (void)n_in; (void)d_ws; (void)ws_size; (void)out_size;
  const float* obs   = (const float*)d_in[0];
  const float* W_enc = (const float*)d_in[1];
  const float* b_enc = (const float*)d_in[2];
  const float* W_f   = (const float*)d_in[3];
  const float* b_f   = (const float*)d_in[4];
  const float* W_dec = (const float*)d_in[5];
  const float* b_dec = (const float*)d_in[6];
  float* out = (float*)d_out;

  // single kernel; does NOT touch d_ws (R4 lesson: serializes behind ws fill)
  gnn_fused<<<dim3(NB / BT), dim3(THREADS), 0, stream>>>(
      obs, W_enc, b_enc, W_f, b_f, W_dec, b_dec, out);
}